// Round 2
// baseline (158.356 us; speedup 1.0000x reference)
//
#include <hip/hip_runtime.h>
#include <hip/hip_fp16.h>
#include <hip/hip_cooperative_groups.h>

namespace cg = cooperative_groups;

typedef __attribute__((ext_vector_type(8))) _Float16 f16x8;
typedef __attribute__((ext_vector_type(4))) _Float16 f16x4;
typedef __attribute__((ext_vector_type(8))) unsigned short u16x8;
typedef __attribute__((ext_vector_type(4))) float f32x4;

constexpr int NT = 256;
constexpr int TILE_SHORTS = 4096;   // 64 rows x 64 fp16 = 8KB tile image

// phys 16B-chunk swizzle: row r, logical chunk c (0..7) -> short offset
__device__ __forceinline__ int swzoff(int row, int c) {
    return row * 64 + ((c ^ (row & 7)) << 3);
}
__device__ __forceinline__ unsigned short f2h_u(float x) {
    return __half_as_ushort(__float2half(x));
}

// ================= fused: convert-tile phase + grid.sync + attn phase ======
// Block (bh,qt) converts K/V tile (bh, tile=qt) to fp16 swizzled images
// (bijective over all 512 tiles), then after the grid barrier runs the
// R0-structure attention for q-tile qt. XCD-pinned: bid%8 selects the bh
// pair, so images are produced and consumed in the same XCD's L2.
__global__ __launch_bounds__(NT, 2) void fused_attn(
    const float* __restrict__ Qg,
    const float* __restrict__ Kg, const float* __restrict__ Vg,
    unsigned short* __restrict__ Kw, unsigned short* __restrict__ Vw,
    float* __restrict__ Og)
{
    __shared__ __align__(16) unsigned short lds[4 * TILE_SHORTS];  // 32 KiB
    const int tid  = threadIdx.x;
    const int lane = tid & 63;
    const int wave = tid >> 6;
    const int a    = lane & 15;
    const int quad = lane >> 4;
    const int m0   = wave * 16;

    // XCD-pinned heavy/light mapping (same as R1): per XCD, CU c gets
    // qt=31-c (bh even) in round 1 of dispatch and qt=c (bh odd) in round 2.
    const int bid = (int)blockIdx.x;
    const int xcd = bid & 7;
    const int y   = bid >> 3;
    const int yy  = y & 31;
    const int bh  = xcd * 2 + (y >= 32);
    const int qt  = (y < 32) ? (31 - yy) : yy;
    const int b = bh >> 3, h = bh & 7;
    const int q0 = qt * 64;

    // ---- Q B-frags early: HBM latency hides under the conversion phase ----
    f16x8 bQ[2];
    {
        const size_t qrowbase = (((size_t)b * 2048 + q0 + m0 + a) * 8 + h) * 64;
        #pragma unroll
        for (int ks = 0; ks < 2; ++ks) {
            const float* src = &Qg[qrowbase + ks * 32 + quad * 8];
            float4 x = *(const float4*)src, y2 = *(const float4*)(src + 4);
            u16x8 o;
            o[0] = f2h_u(x.x); o[1] = f2h_u(x.y); o[2] = f2h_u(x.z); o[3] = f2h_u(x.w);
            o[4] = f2h_u(y2.x); o[5] = f2h_u(y2.y); o[6] = f2h_u(y2.z); o[7] = f2h_u(y2.w);
            bQ[ks] = __builtin_bit_cast(f16x8, o);
        }
    }

    // ================= phase 1: convert tile (bh, qt) =================
    {
        float* Vl = (float*)lds;          // 64*68 f32 = 17.4 KB, aliased
        const int tile = qt;
        const size_t gbase = (((size_t)b * 2048 + tile * 64) * 8 + h) * 64;

        // stage V tile f32 into LDS (coalesced)
        #pragma unroll
        for (int j = 0; j < 4; ++j) {
            int id = j * 256 + tid, row = id >> 4, c4 = id & 15;
            *(float4*)&Vl[row * 68 + c4 * 4] =
                *(const float4*)&Vg[gbase + (size_t)row * 512 + c4 * 4];
        }

        // K image: row-major fp16, 16B chunks XOR-swizzled (no LDS dep)
        unsigned short* Ko = Kw + (size_t)(bh * 32 + tile) * TILE_SHORTS;
        #pragma unroll
        for (int j = 0; j < 2; ++j) {
            int id = j * 256 + tid, row = id >> 3, c = id & 7;
            const float* src = &Kg[gbase + (size_t)row * 512 + c * 8];
            float4 x = *(const float4*)src, y2 = *(const float4*)(src + 4);
            u16x8 o;
            o[0] = f2h_u(x.x); o[1] = f2h_u(x.y); o[2] = f2h_u(x.z); o[3] = f2h_u(x.w);
            o[4] = f2h_u(y2.x); o[5] = f2h_u(y2.y); o[6] = f2h_u(y2.z); o[7] = f2h_u(y2.w);
            *(u16x8*)&Ko[swzoff(row, c)] = o;
        }
        __syncthreads();

        // V^T image, k-permuted so one b128 = the 4 B-frags of 16x16x16 PV
        unsigned short* Vo = Vw + (size_t)(bh * 32 + tile) * TILE_SHORTS;
        #pragma unroll
        for (int j = 0; j < 2; ++j) {
            int id = j * 256 + tid, vrow = id >> 3, g = id & 7;
            u16x8 o;
            #pragma unroll
            for (int jj = 0; jj < 8; ++jj) {
                int kk = ((g & 1) * 2 + (jj >> 2)) * 16 + (g >> 1) * 4 + (jj & 3);
                o[jj] = f2h_u(Vl[kk * 68 + vrow]);
            }
            *(u16x8*)&Vo[swzoff(vrow, g)] = o;
        }
    }

    // all 512 tile images complete + visible device-wide
    cg::this_grid().sync();

    // ================= phase 2: attention (R0 structure) =================
    unsigned short* const Kb = lds;                    // 2 buffers
    unsigned short* const Vb = lds + 2 * TILE_SHORTS;  // 2 buffers

    const unsigned short* Ktiles = Kw + (size_t)bh * 32 * TILE_SHORTS;
    const unsigned short* Vtiles = Vw + (size_t)bh * 32 * TILE_SHORTS;

    // register-staged tile prefetch (byte-copy of pre-swizzled images)
    u16x8 rK[2], rV[2];
    auto gload = [&](int kt) {
        const u16x8* kg = (const u16x8*)(Ktiles + (size_t)kt * TILE_SHORTS);
        const u16x8* vg = (const u16x8*)(Vtiles + (size_t)kt * TILE_SHORTS);
        rK[0] = kg[tid * 2]; rK[1] = kg[tid * 2 + 1];
        rV[0] = vg[tid * 2]; rV[1] = vg[tid * 2 + 1];
    };
    gload(0);

    f32x4 oacc[4];
    #pragma unroll
    for (int n = 0; n < 4; ++n) oacc[n] = (f32x4){0.f, 0.f, 0.f, 0.f};
    float den_l = 0.f;

    union U8 { u16x8 u; f16x4 q[2]; f16x8 f; };

    for (int kt = 0; kt <= qt; ++kt) {
        const int buf = kt & 1;
        u16x8* kd = (u16x8*)(Kb + buf * TILE_SHORTS);
        u16x8* vd = (u16x8*)(Vb + buf * TILE_SHORTS);
        kd[tid * 2] = rK[0]; kd[tid * 2 + 1] = rK[1];
        vd[tid * 2] = rV[0]; vd[tid * 2 + 1] = rV[1];
        __syncthreads();   // single barrier: buf complete; WAR is 1 barrier back
        if (kt < qt) gload(kt + 1);   // drains during this tile's compute

        const unsigned short* Kc = Kb + buf * TILE_SHORTS;
        const unsigned short* Vc = Vb + buf * TILE_SHORTS;

        // ---- S^T = K·Q^T per 16-row k-strip: C-layout == A-layout of S ----
        f32x4 sacc[4];
        #pragma unroll
        for (int s = 0; s < 4; ++s) sacc[s] = (f32x4){0.f, 0.f, 0.f, 0.f};
        #pragma unroll
        for (int s = 0; s < 4; ++s) {
            #pragma unroll
            for (int ks = 0; ks < 2; ++ks) {
                U8 ak; ak.u = *(const u16x8*)&Kc[swzoff(s * 16 + a, ks * 4 + quad)];
                sacc[s] = __builtin_amdgcn_mfma_f32_16x16x32_f16(ak.f, bQ[ks], sacc[s], 0, 0, 0);
            }
        }

        // ---- square, mask (diag), den, convert in-register ----
        const bool diag = (kt == qt);
        f16x4 aS[4];
        #pragma unroll
        for (int s = 0; s < 4; ++s) {
            float p[4];
            #pragma unroll
            for (int r = 0; r < 4; ++r) {
                float d0 = sacc[s][r];
                float v = d0 * d0;
                if (diag && (s * 16 + quad * 4 + r) > (m0 + a)) v = 0.f;
                p[r] = v;
            }
            den_l += (p[0] + p[1]) + (p[2] + p[3]);
            aS[s] = (f16x4){(_Float16)p[0], (_Float16)p[1], (_Float16)p[2], (_Float16)p[3]};
        }

        // ---- PV: O += S·V via 16x16x16, S^T C-regs feed A directly ----
        #pragma unroll
        for (int n = 0; n < 4; ++n) {
            U8 va, vb;
            va.u = *(const u16x8*)&Vc[swzoff(n * 16 + a, quad * 2)];
            vb.u = *(const u16x8*)&Vc[swzoff(n * 16 + a, quad * 2 + 1)];
            oacc[n] = __builtin_amdgcn_mfma_f32_16x16x16f16(aS[0], va.q[0], oacc[n], 0, 0, 0);
            oacc[n] = __builtin_amdgcn_mfma_f32_16x16x16f16(aS[1], va.q[1], oacc[n], 0, 0, 0);
            oacc[n] = __builtin_amdgcn_mfma_f32_16x16x16f16(aS[2], vb.q[0], oacc[n], 0, 0, 0);
            oacc[n] = __builtin_amdgcn_mfma_f32_16x16x16f16(aS[3], vb.q[1], oacc[n], 0, 0, 0);
        }
    }

    // ---- den: reduce across quads (same q=a), then gather per output row ----
    den_l += __shfl_xor(den_l, 16);
    den_l += __shfl_xor(den_l, 32);

    float invz[4];
    #pragma unroll
    for (int r = 0; r < 4; ++r) {
        float dq = __shfl(den_l, quad * 4 + r);   // lane holding a == quad*4+r
        invz[r] = 1.0f / (dq + 1e-5f);
    }

    #pragma unroll
    for (int n = 0; n < 4; ++n) {
        #pragma unroll
        for (int r = 0; r < 4; ++r) {
            int t = q0 + m0 + quad * 4 + r;
            int v = n * 16 + a;
            Og[(((size_t)b * 2048 + t) * 8 + h) * 64 + v] = oacc[n][r] * invz[r];
        }
    }
}

extern "C" void kernel_launch(void* const* d_in, const int* in_sizes, int n_in,
                              void* d_out, int out_size, void* d_ws, size_t ws_size,
                              hipStream_t stream) {
    const float* Q = (const float*)d_in[0];
    const float* K = (const float*)d_in[1];
    const float* V = (const float*)d_in[2];
    float* O = (float*)d_out;
    unsigned short* Kw = (unsigned short*)d_ws;                 // 4 MB
    unsigned short* Vw = Kw + (size_t)16 * 32 * TILE_SHORTS;    // 4 MB

    void* args[] = {(void*)&Q, (void*)&K, (void*)&V,
                    (void*)&Kw, (void*)&Vw, (void*)&O};
    hipLaunchCooperativeKernel((const void*)fused_attn,
                               dim3(512), dim3(NT), args, 0, stream);
}

// Round 3
// 104.506 us; speedup vs baseline: 1.5153x; 1.5153x over previous
//
#include <hip/hip_runtime.h>
#include <hip/hip_fp16.h>

typedef __attribute__((ext_vector_type(8))) _Float16 f16x8;
typedef __attribute__((ext_vector_type(4))) _Float16 f16x4;
typedef __attribute__((ext_vector_type(8))) unsigned short u16x8;
typedef __attribute__((ext_vector_type(4))) float f32x4;

constexpr int NT = 256;
constexpr int TILE_SHORTS = 4096;   // 64 rows x 64 fp16 = 8KB tile image

// phys 16B-chunk swizzle: row r, logical chunk c (0..7) -> short offset
// (kept from the LDS era; for global reads it still gives 64B-aligned
//  coverage per row on the K side and line-level coverage on V)
__device__ __forceinline__ int swzoff(int row, int c) {
    return row * 64 + ((c ^ (row & 7)) << 3);
}
__device__ __forceinline__ unsigned short f2h_u(float x) {
    return __half_as_ushort(__float2half(x));
}

// ============ pre-pass: f32 -> fp16 swizzled tile images in ws ============
// XCD-pinned: bid%8 == bh>>1, image produced in the consuming XCD's L2.
__global__ __launch_bounds__(256, 4) void prepass(
    const float* __restrict__ Kg, const float* __restrict__ Vg,
    unsigned short* __restrict__ Kw, unsigned short* __restrict__ Vw)
{
    __shared__ __align__(16) float Vl[64 * 68];
    const int bid  = (int)blockIdx.x;          // 0..511
    const int xcd  = bid & 7;
    const int y    = bid >> 3;                 // 0..63
    const int bh   = xcd * 2 + (y >= 32);      // 2 bh per XCD
    const int tile = y & 31;                   // 0..31
    const int b = bh >> 3, h = bh & 7;
    const int tid = threadIdx.x;
    const size_t gbase = (((size_t)b * 2048 + tile * 64) * 8 + h) * 64;

    // stage V tile f32 into LDS (coalesced)
    #pragma unroll
    for (int j = 0; j < 4; ++j) {
        int id = j * 256 + tid, row = id >> 4, c4 = id & 15;
        *(float4*)&Vl[row * 68 + c4 * 4] =
            *(const float4*)&Vg[gbase + (size_t)row * 512 + c4 * 4];
    }

    // K image: row-major fp16, 16B chunks XOR-swizzled
    unsigned short* Ko = Kw + (size_t)(bh * 32 + tile) * TILE_SHORTS;
    #pragma unroll
    for (int j = 0; j < 2; ++j) {
        int id = j * 256 + tid, row = id >> 3, c = id & 7;
        const float* src = &Kg[gbase + (size_t)row * 512 + c * 8];
        float4 x = *(const float4*)src, y2 = *(const float4*)(src + 4);
        u16x8 o;
        o[0] = f2h_u(x.x); o[1] = f2h_u(x.y); o[2] = f2h_u(x.z); o[3] = f2h_u(x.w);
        o[4] = f2h_u(y2.x); o[5] = f2h_u(y2.y); o[6] = f2h_u(y2.z); o[7] = f2h_u(y2.w);
        *(u16x8*)&Ko[swzoff(row, c)] = o;
    }
    __syncthreads();

    // V^T image, k-permuted so one b128 = the 4 B-frags of 16x16x16 PV:
    // store at k' = quad*16 + c*4 + i the element k = c*16 + quad*4 + i
    unsigned short* Vo = Vw + (size_t)(bh * 32 + tile) * TILE_SHORTS;
    #pragma unroll
    for (int j = 0; j < 2; ++j) {
        int id = j * 256 + tid, vrow = id >> 3, g = id & 7;
        u16x8 o;
        #pragma unroll
        for (int jj = 0; jj < 8; ++jj) {
            int kk = ((g & 1) * 2 + (jj >> 2)) * 16 + (g >> 1) * 4 + (jj & 3);
            o[jj] = f2h_u(Vl[kk * 68 + vrow]);
        }
        *(u16x8*)&Vo[swzoff(vrow, g)] = o;
    }
}

// ======= main kernel: barrier-free, LDS-free, L2-direct fragment stream =====
// Per-XCD image working set = 1MB (2 bh) -> L2-resident. Each wave streams
// its MFMA fragments straight from the images; A/B register double-stage
// gives each load one full compute phase of latency cover. No __syncthreads.
__global__ __launch_bounds__(NT, 2) void attn_pow2_f16(
    const float* __restrict__ Qg,
    const unsigned short* __restrict__ Kw, const unsigned short* __restrict__ Vw,
    float* __restrict__ Og)
{
    const int tid  = threadIdx.x;
    const int lane = tid & 63;
    const int wave = tid >> 6;
    const int a    = lane & 15;
    const int quad = lane >> 4;
    const int m0   = wave * 16;

    // XCD-pinned heavy/light mapping: CU c of each XCD gets qt=31-c and qt=c
    const int bid = (int)blockIdx.x;
    const int xcd = bid & 7;
    const int y   = bid >> 3;
    const int yy  = y & 31;
    const int bh  = xcd * 2 + (y >= 32);
    const int qt  = (y < 32) ? (31 - yy) : yy;
    const int b = bh >> 3, h = bh & 7;
    const int q0 = qt * 64;

    // ---- Q B-frags from global f32: B[n=q=a][k=d=ks*32+quad*8+j] ----
    f16x8 bQ[2];
    {
        const size_t qrowbase = (((size_t)b * 2048 + q0 + m0 + a) * 8 + h) * 64;
        #pragma unroll
        for (int ks = 0; ks < 2; ++ks) {
            const float* src = &Qg[qrowbase + ks * 32 + quad * 8];
            float4 x = *(const float4*)src, y2 = *(const float4*)(src + 4);
            u16x8 o;
            o[0] = f2h_u(x.x); o[1] = f2h_u(x.y); o[2] = f2h_u(x.z); o[3] = f2h_u(x.w);
            o[4] = f2h_u(y2.x); o[5] = f2h_u(y2.y); o[6] = f2h_u(y2.z); o[7] = f2h_u(y2.w);
            bQ[ks] = __builtin_bit_cast(f16x8, o);
        }
    }

    const unsigned short* Ktiles = Kw + (size_t)bh * 32 * TILE_SHORTS;
    const unsigned short* Vtiles = Vw + (size_t)bh * 32 * TILE_SHORTS;

    // per-lane fragment short-offsets within a tile image (fixed across kt)
    int offK[8];   // [s*2+ks]
    #pragma unroll
    for (int s = 0; s < 4; ++s)
        #pragma unroll
        for (int ks = 0; ks < 2; ++ks)
            offK[s * 2 + ks] = swzoff(s * 16 + a, ks * 4 + quad);
    int offV[8];   // [n*2+half]
    #pragma unroll
    for (int n = 0; n < 4; ++n)
        #pragma unroll
        for (int h2 = 0; h2 < 2; ++h2)
            offV[n * 2 + h2] = swzoff(n * 16 + a, quad * 2 + h2);

    u16x8 kA[8], vA[8], kB[8], vB[8];

#define LOADSTAGE(kr, vr, ktile) do {                                          \
        const unsigned short* Kt_ = Ktiles + (size_t)(ktile) * TILE_SHORTS;    \
        const unsigned short* Vt_ = Vtiles + (size_t)(ktile) * TILE_SHORTS;    \
        _Pragma("unroll")                                                      \
        for (int i_ = 0; i_ < 8; ++i_) kr[i_] = *(const u16x8*)&Kt_[offK[i_]]; \
        _Pragma("unroll")                                                      \
        for (int i_ = 0; i_ < 8; ++i_) vr[i_] = *(const u16x8*)&Vt_[offV[i_]]; \
    } while (0)

    f32x4 oacc[4];
    #pragma unroll
    for (int n = 0; n < 4; ++n) oacc[n] = (f32x4){0.f, 0.f, 0.f, 0.f};
    float den_l = 0.f;

    union U8 { u16x8 u; f16x4 q[2]; f16x8 f; };

#define COMPUTE(kr, vr, diag) do {                                             \
        f32x4 sacc[4];                                                         \
        _Pragma("unroll")                                                      \
        for (int s = 0; s < 4; ++s) sacc[s] = (f32x4){0.f, 0.f, 0.f, 0.f};     \
        __builtin_amdgcn_s_setprio(1);                                         \
        _Pragma("unroll")                                                      \
        for (int s = 0; s < 4; ++s) {                                          \
            _Pragma("unroll")                                                  \
            for (int ks = 0; ks < 2; ++ks) {                                   \
                U8 ak; ak.u = kr[s * 2 + ks];                                  \
                sacc[s] = __builtin_amdgcn_mfma_f32_16x16x32_f16(              \
                    ak.f, bQ[ks], sacc[s], 0, 0, 0);                           \
            }                                                                  \
        }                                                                      \
        __builtin_amdgcn_s_setprio(0);                                         \
        f16x4 aS[4];                                                           \
        _Pragma("unroll")                                                      \
        for (int s = 0; s < 4; ++s) {                                          \
            float p0 = sacc[s][0], p1 = sacc[s][1], p2 = sacc[s][2], p3 = sacc[s][3]; \
            p0 *= p0; p1 *= p1; p2 *= p2; p3 *= p3;                            \
            if (diag) {                                                        \
                int kbase = s * 16 + quad * 4, qrow = m0 + a;                  \
                if (kbase + 0 > qrow) p0 = 0.f;                                \
                if (kbase + 1 > qrow) p1 = 0.f;                                \
                if (kbase + 2 > qrow) p2 = 0.f;                                \
                if (kbase + 3 > qrow) p3 = 0.f;                                \
            }                                                                  \
            den_l += (p0 + p1) + (p2 + p3);                                    \
            aS[s] = (f16x4){(_Float16)p0, (_Float16)p1, (_Float16)p2, (_Float16)p3}; \
        }                                                                      \
        __builtin_amdgcn_s_setprio(1);                                         \
        _Pragma("unroll")                                                      \
        for (int n = 0; n < 4; ++n) {                                          \
            U8 va, vb;                                                         \
            va.u = vr[n * 2]; vb.u = vr[n * 2 + 1];                            \
            oacc[n] = __builtin_amdgcn_mfma_f32_16x16x16f16(aS[0], va.q[0], oacc[n], 0, 0, 0); \
            oacc[n] = __builtin_amdgcn_mfma_f32_16x16x16f16(aS[1], va.q[1], oacc[n], 0, 0, 0); \
            oacc[n] = __builtin_amdgcn_mfma_f32_16x16x16f16(aS[2], vb.q[0], oacc[n], 0, 0, 0); \
            oacc[n] = __builtin_amdgcn_mfma_f32_16x16x16f16(aS[3], vb.q[1], oacc[n], 0, 0, 0); \
        }                                                                      \
        __builtin_amdgcn_s_setprio(0);                                         \
    } while (0)

    // prologue: fill both stages
    LOADSTAGE(kA, vA, 0);
    if (qt >= 1) LOADSTAGE(kB, vB, 1);

    int kt = 0;
    for (;;) {
        COMPUTE(kA, vA, kt == qt);
        if (kt + 2 <= qt) LOADSTAGE(kA, vA, kt + 2);   // lands during B phase
        if (++kt > qt) break;
        COMPUTE(kB, vB, kt == qt);
        if (kt + 2 <= qt) LOADSTAGE(kB, vB, kt + 2);   // lands during A phase
        if (++kt > qt) break;
    }

#undef COMPUTE
#undef LOADSTAGE

    // ---- den: reduce across quads (same q=a), then gather per output row ----
    den_l += __shfl_xor(den_l, 16);
    den_l += __shfl_xor(den_l, 32);

    float invz[4];
    #pragma unroll
    for (int r = 0; r < 4; ++r) {
        float dq = __shfl(den_l, quad * 4 + r);   // lane holding a == quad*4+r
        invz[r] = 1.0f / (dq + 1e-5f);
    }

    #pragma unroll
    for (int n = 0; n < 4; ++n) {
        #pragma unroll
        for (int r = 0; r < 4; ++r) {
            int t = q0 + m0 + quad * 4 + r;
            int v = n * 16 + a;
            Og[(((size_t)b * 2048 + t) * 8 + h) * 64 + v] = oacc[n][r] * invz[r];
        }
    }
}

extern "C" void kernel_launch(void* const* d_in, const int* in_sizes, int n_in,
                              void* d_out, int out_size, void* d_ws, size_t ws_size,
                              hipStream_t stream) {
    const float* Q = (const float*)d_in[0];
    const float* K = (const float*)d_in[1];
    const float* V = (const float*)d_in[2];
    float* O = (float*)d_out;
    unsigned short* Kw = (unsigned short*)d_ws;                 // 4 MB
    unsigned short* Vw = Kw + (size_t)16 * 32 * TILE_SHORTS;    // 4 MB

    prepass<<<dim3(512), 256, 0, stream>>>(K, V, Kw, Vw);
    attn_pow2_f16<<<dim3(512), NT, 0, stream>>>(Q, Kw, Vw, O);
}